// Round 7
// baseline (260.903 us; speedup 1.0000x reference)
//
#include <hip/hip_runtime.h>
#include <cstdint>

typedef unsigned short ushort_t;
typedef __bf16 bf16x8 __attribute__((ext_vector_type(8)));
typedef float f32x4 __attribute__((ext_vector_type(4)));

#define B_ 8
#define T_ 2048
#define D_ 1024
#define M_ (B_ * T_)        // 16384
#define NCHUNK 64
#define CHUNKLEN 32         // 64*32 = 2048 = T_

__device__ __forceinline__ ushort_t f2bf(float f) {
    union { float f; uint32_t u; } v; v.f = f;
    uint32_t u = v.u;
    uint32_t r = (u + 0x7fffu + ((u >> 16) & 1u)) >> 16;
    return (ushort_t)r;
}
__device__ __forceinline__ float bf2f(ushort_t h) {
    union { uint32_t u; float f; } v; v.u = ((uint32_t)h) << 16;
    return v.f;
}
__device__ __forceinline__ uint32_t pack2bf(float lo, float hi) {
    return (uint32_t)f2bf(lo) | ((uint32_t)f2bf(hi) << 16);
}

__device__ __forceinline__ void async16(const ushort_t* g, ushort_t* l) {
    __builtin_amdgcn_global_load_lds(
        (const __attribute__((address_space(1))) void*)g,
        (__attribute__((address_space(3))) void*)l, 16, 0, 0);
}

// ------- one-shot cast: x + Wq + Wk + Wv -> bf16, 8 elems/thread -------
// loads 2x float4 (32 B/lane), stores one uint4 (16 B/lane, G13 sweet spot).
__global__ __launch_bounds__(256) void cast_all(
    const float* __restrict__ x, const float* __restrict__ wq,
    const float* __restrict__ wk, const float* __restrict__ wv,
    ushort_t* __restrict__ xb, ushort_t* __restrict__ Wb) {
    const int nx8 = M_ * D_ / 8, nw8 = D_ * D_ / 8;
    int i = blockIdx.x * blockDim.x + threadIdx.x;
    const float* src; ushort_t* dstp; int si;
    if (i < nx8) {
        src = x; si = i; dstp = xb + (size_t)i * 8;
    } else {
        int j = i - nx8;
        dstp = Wb + (size_t)j * 8;
        if (j < nw8)          { src = wq; si = j; }
        else if (j < 2 * nw8) { src = wk; si = j - nw8; }
        else                  { src = wv; si = j - 2 * nw8; }
    }
    const float4 a = ((const float4*)src)[si * 2];
    const float4 b = ((const float4*)src)[si * 2 + 1];
    uint4 o;
    o.x = pack2bf(a.x, a.y);
    o.y = pack2bf(a.z, a.w);
    o.z = pack2bf(b.x, b.y);
    o.w = pack2bf(b.z, b.w);
    *(uint4*)dstp = o;
}

// ============ Unified QKV GEMM (2-phase dbuf, BK=32) + fused chunk-scan ============
// Base = round-4 structure (best median-toolchain variant): SIX distinct 8 KB
// LDS arrays (two static buffers per matrix), K-loop unrolled by 2 with buffer
// names hard-coded (no alias analysis needed to keep in-flight global_load_lds
// independent of current-tile ds_reads), ONE __syncthreads() per K-tile placed
// AFTER the MFMA cluster.  Session history (same logic, 6 containers):
//   dyn-indexed 2-phase: 58% / 27% MfmaUtil (toolchain lottery)
//   static 2-phase:      39%
//   3-deep counted vmcnt + sched_barrier fences: 34% (fences pin order, hurt)
//   static 2-phase + setprio(T5): 41.8%  <- current best, KEPT (cleared the
//     pre-committed 2% bar vs R4 on a clock-matched container)
// Ceiling note: with 4 waves/block (2x2 wave grid), LDS amplification
// (write 24 KB + read 48 KB per tile per block, 2 blocks/CU -> 563 cyc
// vs 310 cyc MFMA issue) caps this structure at ~55% MfmaUtil.
// __launch_bounds__(256,2): DO NOT raise to 3 — accumulators spill
// (round-3: FETCH 74 MB -> 1.06 GB, MfmaUtil 6%, 685 us).
// Swizzle (4 slots of 16 B per row): slot s of row r holds global chunk
// g = s ^ ((r>>1)&3); read side applies the same involution -> 2-way (free).
// global_load_lds dest stays wave-linear; permutation applied to the
// per-lane GLOBAL source address (both-sides rule).
// blocks [0,512):   q-mode:  qb = x@Wq^T+bq (bf16), n-tile 256
// blocks [512,1536): kv-mode: kvb = (x@Wk^T+bk)*(x@Wv^T+bv) (bf16), n-tile 128,
//   plus chunk sums S[b,c,d] = sum_tau dec^(31-tau) kv[32c+tau,d] via registers.
__global__ __launch_bounds__(256, 2) void gemm_qkv(
    const ushort_t* __restrict__ xb, const ushort_t* __restrict__ Wq,
    const ushort_t* __restrict__ Wk, const ushort_t* __restrict__ Wv,
    const float* __restrict__ bq, const float* __restrict__ bk,
    const float* __restrict__ bv, const float* __restrict__ decay,
    ushort_t* __restrict__ qb, ushort_t* __restrict__ kvb,
    float* __restrict__ S) {
    __shared__ ushort_t As0[128 * 32];
    __shared__ ushort_t As1[128 * 32];
    __shared__ ushort_t B00[128 * 32];
    __shared__ ushort_t B01[128 * 32];
    __shared__ ushort_t B10[128 * 32];
    __shared__ ushort_t B11[128 * 32];

    const int idx = blockIdx.x;
    const bool qmode = idx < 512;
    int mb, n0;
    const ushort_t *W0, *W1;
    if (qmode) {
        mb = idx & 127; n0 = (idx >> 7) * 256;
        W0 = Wq + (size_t)n0 * D_;
        W1 = Wq + (size_t)(n0 + 128) * D_;
    } else {
        const int j = idx - 512;
        mb = j & 127; n0 = (j >> 7) * 128;
        W0 = Wk + (size_t)n0 * D_;
        W1 = Wv + (size_t)n0 * D_;
    }
    const int m0 = mb * 128;

    const int t = threadIdx.x;
    const int lane = t & 63, wv = t >> 6;
    const int wr = (wv >> 1) * 64, wc = (wv & 1) * 64;

    f32x4 acc0[4][4], acc1[4][4];
#pragma unroll
    for (int i = 0; i < 4; ++i)
#pragma unroll
        for (int j = 0; j < 4; ++j) {
            acc0[i][j] = (f32x4){0.f, 0.f, 0.f, 0.f};
            acc1[i][j] = (f32x4){0.f, 0.f, 0.f, 0.f};
        }

    // ---- staging geometry (per 8 KB tile = 512 x 16B chunks, 2/thread) ----
    // thread t covers chunk c = t + p*256  ->  row = c>>2, slot = c&3.
    // source global chunk for (row, slot): g = slot ^ ((row>>1)&3);
    // note row(p=1) = row(p=0)+64 leaves (row>>1)&3 unchanged.
    const int rs = t >> 2;                         // base row 0..63
    const int g = (t & 3) ^ ((t >> 3) & 3);        // swizzled source chunk
    const int scol = g * 8;                        // source col (ushorts)

    // ---- read-side swizzled column (quad q reads logical chunk q) ----
    const int quad = lane >> 4;
    const int rsw = ((lane & 15) >> 1) & 3;        // (row>>1)&3 for this lane
    const int cs = (quad ^ rsw) * 8;               // ushort offset within row
    const int rowa = wr + (lane & 15);
    const int rowb = wc + (lane & 15);

#define STAGE(A_, P_, Q_, ktv)                                               \
    do {                                                                     \
        const int k0s = (ktv) * 32;                                          \
        _Pragma("unroll")                                                    \
        for (int p = 0; p < 2; ++p) {                                        \
            const int rp = rs + p * 64;                                      \
            const int Lofs = (t + p * 256) * 8;                              \
            async16(xb + (size_t)(m0 + rp) * D_ + k0s + scol, &A_[Lofs]);    \
            async16(W0 + (size_t)rp * D_ + k0s + scol, &P_[Lofs]);           \
            async16(W1 + (size_t)rp * D_ + k0s + scol, &Q_[Lofs]);           \
        }                                                                    \
    } while (0)

// T5: setprio(1) around the pure-MFMA cluster only (fragment ds_reads stay
// at prio 0 so the staging waves of the other resident block can interleave).
#define COMPUTE(A_, P_, Q_)                                                  \
    do {                                                                     \
        bf16x8 af[4], b08[4], b18[4];                                        \
        _Pragma("unroll")                                                    \
        for (int i = 0; i < 4; ++i)                                          \
            af[i] = *(const bf16x8*)&A_[(rowa + i * 16) * 32 + cs];          \
        _Pragma("unroll")                                                    \
        for (int j = 0; j < 4; ++j) {                                        \
            b08[j] = *(const bf16x8*)&P_[(rowb + j * 16) * 32 + cs];         \
            b18[j] = *(const bf16x8*)&Q_[(rowb + j * 16) * 32 + cs];         \
        }                                                                    \
        __builtin_amdgcn_s_setprio(1);                                       \
        _Pragma("unroll")                                                    \
        for (int i = 0; i < 4; ++i)                                          \
            _Pragma("unroll")                                                \
            for (int j = 0; j < 4; ++j) {                                    \
                acc0[i][j] = __builtin_amdgcn_mfma_f32_16x16x32_bf16(        \
                    af[i], b08[j], acc0[i][j], 0, 0, 0);                     \
                acc1[i][j] = __builtin_amdgcn_mfma_f32_16x16x32_bf16(        \
                    af[i], b18[j], acc1[i][j], 0, 0, 0);                     \
            }                                                                \
        __builtin_amdgcn_s_setprio(0);                                       \
    } while (0)

    // prologue: stage K-tile 0 into buffer set 0
    STAGE(As0, B00, B10, 0);
    __syncthreads();

    for (int kt = 0; kt < 32; kt += 2) {
        // half A: stage kt+1 into set 1, compute kt from set 0
        STAGE(As1, B01, B11, kt + 1);
        COMPUTE(As0, B00, B10);
        __syncthreads();   // drains set-1 stage; set-0 free to overwrite

        // half B: stage kt+2 into set 0, compute kt+1 from set 1
        if (kt + 2 < 32) STAGE(As0, B00, B10, kt + 2);
        COMPUTE(As1, B01, B11);
        __syncthreads();   // drains set-0 stage; set-1 free to overwrite
    }
#undef STAGE
#undef COMPUTE

    // epilogue: C/D layout col=lane&15, row=quad*4+r
    const int colq = lane & 15;
    const int rowq = quad * 4;

    if (qmode) {
        const float* bias0 = bq + n0;
        const float* bias1 = bq + n0 + 128;
#pragma unroll
        for (int i = 0; i < 4; ++i) {
#pragma unroll
            for (int j = 0; j < 4; ++j) {
                const int c = wc + j * 16 + colq;
                const float bv0 = bias0[c], bv1 = bias1[c];
#pragma unroll
                for (int r = 0; r < 4; ++r) {
                    const int rg = m0 + wr + i * 16 + rowq + r;
                    qb[(size_t)rg * D_ + n0 + c]       = f2bf(acc0[i][j][r] + bv0);
                    qb[(size_t)rg * D_ + n0 + 128 + c] = f2bf(acc1[i][j][r] + bv1);
                }
            }
        }
    } else {
        // kv-mode, row-outer store order (full 128B row segments -> no partial
        // line writeback). weight(localrow) = dec^(31-16(i&1)-4*quad-r).
        const float* bias0 = bk + n0;
        const float* bias1 = bv + n0;
        const int bidx = m0 >> 11;
        const int cbase = ((m0 & 2047) >> 5) + (wr >> 5);
        int cj[4];
        float bv0a[4], bv1a[4], d1a[4], d2a[4], d3a[4], P0a[4], P1a[4];
#pragma unroll
        for (int j = 0; j < 4; ++j) {
            const int c = wc + j * 16 + colq;
            cj[j] = c;
            bv0a[j] = bias0[c];
            bv1a[j] = bias1[c];
            const float dec = decay[n0 + c];
            const float d2 = dec * dec, d4 = d2 * d2;
            const float d8 = d4 * d4, d16 = d8 * d8;
            d1a[j] = dec; d2a[j] = d2; d3a[j] = d2 * dec;
            const float P1 = (quad == 0) ? (d8 * d4) : ((quad == 1) ? d8 : ((quad == 2) ? d4 : 1.0f));
            P1a[j] = P1;
            P0a[j] = d16 * P1;
        }
        float s0[4], s1[4];
#pragma unroll
        for (int j = 0; j < 4; ++j) { s0[j] = 0.f; s1[j] = 0.f; }

#pragma unroll
        for (int i = 0; i < 4; ++i) {
#pragma unroll
            for (int r = 0; r < 4; ++r) {
                const int rg = m0 + wr + i * 16 + rowq + r;
                ushort_t* rowp = kvb + (size_t)rg * D_ + n0;
#pragma unroll
                for (int j = 0; j < 4; ++j) {
                    const float kf = acc0[i][j][r] + bv0a[j];
                    const float vf = acc1[i][j][r] + bv1a[j];
                    const float kvf = kf * vf;
                    rowp[cj[j]] = f2bf(kvf);
                    const float w3 = (r == 0) ? d3a[j] : ((r == 1) ? d2a[j] : ((r == 2) ? d1a[j] : 1.0f));
                    const float wgt = ((i & 1) ? P1a[j] : P0a[j]) * w3;
                    if (i < 2) s0[j] = fmaf(kvf, wgt, s0[j]);
                    else       s1[j] = fmaf(kvf, wgt, s1[j]);
                }
            }
        }
#pragma unroll
        for (int j = 0; j < 4; ++j) {
            s0[j] += __shfl_xor(s0[j], 16, 64);
            s0[j] += __shfl_xor(s0[j], 32, 64);
            s1[j] += __shfl_xor(s1[j], 16, 64);
            s1[j] += __shfl_xor(s1[j], 32, 64);
        }
        if (quad == 0) {
#pragma unroll
            for (int j = 0; j < 4; ++j) {
                const int cg = n0 + cj[j];
                S[(((size_t)bidx * NCHUNK) + cbase) * D_ + cg]     = s0[j];
                S[(((size_t)bidx * NCHUNK) + cbase + 1) * D_ + cg] = s1[j];
            }
        }
    }
}

// ------- scan final: redundant carry-Horner over S, replay, out = q*mem -------
// 1024 blocks (b, chunk, D-half) as before (same 2048-wave parallelism), but
// 128 threads x 4 elems: ushort4 loads (8 B/lane) + float4 stores (16 B/lane)
// instead of ushort2/float2 — G13 width fix, numerics order-identical.
// Prefix loop batches 4 rows of independent loads per step, fma order exact.
__global__ __launch_bounds__(128) void scan_final2(
    const ushort_t* __restrict__ kvb, const ushort_t* __restrict__ qb,
    const float* __restrict__ decay, const float* __restrict__ S,
    float* __restrict__ out) {
    const int bid = blockIdx.x;
    const int b = bid >> 7;             // 128 blocks per batch
    const int c = (bid >> 1) & 63;
    const int dh = bid & 1;
    const int d0 = dh * 512 + threadIdx.x * 4;
    const float4 dc = *(const float4*)&decay[d0];
    float e0 = dc.x, e1 = dc.y, e2 = dc.z, e3 = dc.w;
#pragma unroll
    for (int s = 0; s < 5; ++s) { e0 *= e0; e1 *= e1; e2 *= e2; e3 *= e3; }
    float m0 = 0.f, m1 = 0.f, m2 = 0.f, m3 = 0.f;
    const float* Sb = &S[((size_t)b * NCHUNK) * D_ + d0];
    int cc = 0;
    for (; cc + 4 <= c; cc += 4) {
        const float4 sa = *(const float4*)&Sb[(size_t)(cc + 0) * D_];
        const float4 sb2 = *(const float4*)&Sb[(size_t)(cc + 1) * D_];
        const float4 sc = *(const float4*)&Sb[(size_t)(cc + 2) * D_];
        const float4 sd = *(const float4*)&Sb[(size_t)(cc + 3) * D_];
        m0 = fmaf(e0, m0, sa.x);  m1 = fmaf(e1, m1, sa.y);
        m2 = fmaf(e2, m2, sa.z);  m3 = fmaf(e3, m3, sa.w);
        m0 = fmaf(e0, m0, sb2.x); m1 = fmaf(e1, m1, sb2.y);
        m2 = fmaf(e2, m2, sb2.z); m3 = fmaf(e3, m3, sb2.w);
        m0 = fmaf(e0, m0, sc.x);  m1 = fmaf(e1, m1, sc.y);
        m2 = fmaf(e2, m2, sc.z);  m3 = fmaf(e3, m3, sc.w);
        m0 = fmaf(e0, m0, sd.x);  m1 = fmaf(e1, m1, sd.y);
        m2 = fmaf(e2, m2, sd.z);  m3 = fmaf(e3, m3, sd.w);
    }
    for (; cc < c; ++cc) {
        const float4 s4 = *(const float4*)&Sb[(size_t)cc * D_];
        m0 = fmaf(e0, m0, s4.x);
        m1 = fmaf(e1, m1, s4.y);
        m2 = fmaf(e2, m2, s4.z);
        m3 = fmaf(e3, m3, s4.w);
    }
    size_t base = ((size_t)b * T_ + c * CHUNKLEN) * D_ + d0;
#pragma unroll 8
    for (int i = 0; i < CHUNKLEN; ++i) {
        const size_t o = base + (size_t)i * D_;
        const ushort4 kv = *(const ushort4*)&kvb[o];
        const ushort4 q4 = *(const ushort4*)&qb[o];
        m0 = fmaf(dc.x, m0, bf2f(kv.x));
        m1 = fmaf(dc.y, m1, bf2f(kv.y));
        m2 = fmaf(dc.z, m2, bf2f(kv.z));
        m3 = fmaf(dc.w, m3, bf2f(kv.w));
        *(float4*)&out[o] = make_float4(bf2f(q4.x) * m0, bf2f(q4.y) * m1,
                                        bf2f(q4.z) * m2, bf2f(q4.w) * m3);
    }
}

extern "C" void kernel_launch(void* const* d_in, const int* in_sizes, int n_in,
                              void* d_out, int out_size, void* d_ws, size_t ws_size,
                              hipStream_t stream) {
    const float* x     = (const float*)d_in[0];
    const float* Wq    = (const float*)d_in[1];
    const float* bq    = (const float*)d_in[2];
    const float* Wk    = (const float*)d_in[3];
    const float* bk    = (const float*)d_in[4];
    const float* Wv    = (const float*)d_in[5];
    const float* bv    = (const float*)d_in[6];
    const float* decay = (const float*)d_in[7];
    float* out = (float*)d_out;

    char* ws = (char*)d_ws;
    ushort_t* xb  = (ushort_t*)(ws);                        // 33,554,432 B
    ushort_t* Wb  = (ushort_t*)(ws + 33554432);             //  6,291,456 B
    ushort_t* qb  = (ushort_t*)(ws + 39845888);             // 33,554,432 B
    ushort_t* kvb = (ushort_t*)(ws + 73400320);             // 33,554,432 B
    float*    S   = (float*)(ws + 106954752);               //  2,097,152 B

    ushort_t* Wqb = Wb;
    ushort_t* Wkb = Wb + D_ * D_;
    ushort_t* Wvb = Wb + 2 * D_ * D_;

    const int ncast = (M_ * D_ / 8) + (3 * D_ * D_ / 8);
    cast_all<<<ncast / 256, 256, 0, stream>>>(x, Wq, Wk, Wv, xb, Wb);

    gemm_qkv<<<1536, 256, 0, stream>>>(xb, Wqb, Wkb, Wvb, bq, bk, bv, decay,
                                       qb, kvb, S);

    scan_final2<<<B_ * NCHUNK * 2, 128, 0, stream>>>(kvb, qb, decay, S, out);
}

// Round 8
// 258.496 us; speedup vs baseline: 1.0093x; 1.0093x over previous
//
#include <hip/hip_runtime.h>
#include <cstdint>

typedef unsigned short ushort_t;
typedef __bf16 bf16x8 __attribute__((ext_vector_type(8)));
typedef float f32x4 __attribute__((ext_vector_type(4)));

#define B_ 8
#define T_ 2048
#define D_ 1024
#define M_ (B_ * T_)        // 16384
#define NCHUNK 64
#define CHUNKLEN 32         // 64*32 = 2048 = T_

__device__ __forceinline__ ushort_t f2bf(float f) {
    union { float f; uint32_t u; } v; v.f = f;
    uint32_t u = v.u;
    uint32_t r = (u + 0x7fffu + ((u >> 16) & 1u)) >> 16;
    return (ushort_t)r;
}
__device__ __forceinline__ float bf2f(ushort_t h) {
    union { uint32_t u; float f; } v; v.u = ((uint32_t)h) << 16;
    return v.f;
}
__device__ __forceinline__ uint32_t pack2bf(float lo, float hi) {
    return (uint32_t)f2bf(lo) | ((uint32_t)f2bf(hi) << 16);
}

__device__ __forceinline__ void async16(const ushort_t* g, ushort_t* l) {
    __builtin_amdgcn_global_load_lds(
        (const __attribute__((address_space(1))) void*)g,
        (__attribute__((address_space(3))) void*)l, 16, 0, 0);
}

// ------- W-only cast: Wq + Wk + Wv -> bf16 (12 MB read; x-cast is now
// fused into gemm's reg-staged A-path, eliminating 96 MB of HBM traffic
// and one kernel launch+drain) -------
__global__ __launch_bounds__(256) void cast_w(
    const float* __restrict__ wq, const float* __restrict__ wk,
    const float* __restrict__ wv, ushort_t* __restrict__ Wb) {
    const int nw8 = D_ * D_ / 8;
    int j = blockIdx.x * blockDim.x + threadIdx.x;
    const float* src; int si;
    ushort_t* dstp = Wb + (size_t)j * 8;
    if (j < nw8)          { src = wq; si = j; }
    else if (j < 2 * nw8) { src = wk; si = j - nw8; }
    else                  { src = wv; si = j - 2 * nw8; }
    const float4 a = ((const float4*)src)[si * 2];
    const float4 b = ((const float4*)src)[si * 2 + 1];
    uint4 o;
    o.x = pack2bf(a.x, a.y);
    o.y = pack2bf(a.z, a.w);
    o.z = pack2bf(b.x, b.y);
    o.w = pack2bf(b.z, b.w);
    *(uint4*)dstp = o;
}

// ============ Unified QKV GEMM (2-phase dbuf, BK=32) + fused chunk-scan ============
// Base = round-6 structure (session best, MfmaUtil 41.8%): SIX distinct 8 KB
// LDS arrays (static double-buffer per matrix), K-loop unrolled by 2 with
// buffer names hard-coded, ONE __syncthreads() per K-tile AFTER the MFMA
// cluster, T5 setprio(1) around the MFMA nest (kept: +2.7 pts vs R4).
// NEW this round: A-tile is REG-STAGED from f32 x directly (T14 pattern):
//   STAGE_XLOAD (4x global_load_dwordx4 f32 -> 16 regs, issued early)
//   ... COMPUTE ...
//   STAGE_XWRITE (pack2bf + 2x ds_write_b128, same swizzled layout)
// This fuses the x-cast into the GEMM: compiler's minimal wait before the
// packs is vmcnt(4) (in-order vmcnt; the 4 W global_load_lds issued after
// the x-loads stay in flight), so the 2-phase overlap is preserved.
// Same f2bf on same values -> bitwise-identical numerics.
// Session history (same core logic, 7 containers):
//   dyn-indexed 2-phase: 58% / 27% MfmaUtil (toolchain lottery)
//   static 2-phase: 39%;  3-deep counted vmcnt + fences: 34% (hurt)
//   static 2-phase + setprio: 41.8%  <- base kept here
// __launch_bounds__(256,2): DO NOT raise to 3 — accumulators spill
// (round-3: FETCH 74 MB -> 1.06 GB, MfmaUtil 6%, 685 us).
// Swizzle (4 slots of 16 B per row): slot s of row r holds global chunk
// g = s ^ ((r>>1)&3); read side applies the same involution -> 2-way (free).
// W-path global_load_lds dest stays wave-linear (permutation on the global
// source address); x-path ds_write_b128 targets the same swizzled slots.
// blocks [0,512):   q-mode:  qb = x@Wq^T+bq (bf16), n-tile 256
// blocks [512,1536): kv-mode: kvb = (x@Wk^T+bk)*(x@Wv^T+bv) (bf16), n-tile 128,
//   plus chunk sums S[b,c,d] = sum_tau dec^(31-tau) kv[32c+tau,d] via registers.
__global__ __launch_bounds__(256, 2) void gemm_qkv(
    const float* __restrict__ xf, const ushort_t* __restrict__ Wq,
    const ushort_t* __restrict__ Wk, const ushort_t* __restrict__ Wv,
    const float* __restrict__ bq, const float* __restrict__ bk,
    const float* __restrict__ bv, const float* __restrict__ decay,
    ushort_t* __restrict__ qb, ushort_t* __restrict__ kvb,
    float* __restrict__ S) {
    __shared__ ushort_t As0[128 * 32];
    __shared__ ushort_t As1[128 * 32];
    __shared__ ushort_t B00[128 * 32];
    __shared__ ushort_t B01[128 * 32];
    __shared__ ushort_t B10[128 * 32];
    __shared__ ushort_t B11[128 * 32];

    const int idx = blockIdx.x;
    const bool qmode = idx < 512;
    int mb, n0;
    const ushort_t *W0, *W1;
    if (qmode) {
        mb = idx & 127; n0 = (idx >> 7) * 256;
        W0 = Wq + (size_t)n0 * D_;
        W1 = Wq + (size_t)(n0 + 128) * D_;
    } else {
        const int j = idx - 512;
        mb = j & 127; n0 = (j >> 7) * 128;
        W0 = Wk + (size_t)n0 * D_;
        W1 = Wv + (size_t)n0 * D_;
    }
    const int m0 = mb * 128;

    const int t = threadIdx.x;
    const int lane = t & 63, wv = t >> 6;
    const int wr = (wv >> 1) * 64, wc = (wv & 1) * 64;

    f32x4 acc0[4][4], acc1[4][4];
#pragma unroll
    for (int i = 0; i < 4; ++i)
#pragma unroll
        for (int j = 0; j < 4; ++j) {
            acc0[i][j] = (f32x4){0.f, 0.f, 0.f, 0.f};
            acc1[i][j] = (f32x4){0.f, 0.f, 0.f, 0.f};
        }

    // ---- staging geometry (per 8 KB tile = 512 x 16B chunks, 2/thread) ----
    // thread t covers chunk c = t + p*256  ->  row = c>>2, slot = c&3.
    // source global chunk for (row, slot): g = slot ^ ((row>>1)&3);
    // note row(p=1) = row(p=0)+64 leaves (row>>1)&3 unchanged.
    const int rs = t >> 2;                         // base row 0..63
    const int g = (t & 3) ^ ((t >> 3) & 3);        // swizzled source chunk
    const int scol = g * 8;                        // source col (elements)

    // ---- read-side swizzled column (quad q reads logical chunk q) ----
    const int quad = lane >> 4;
    const int rsw = ((lane & 15) >> 1) & 3;        // (row>>1)&3 for this lane
    const int cs = (quad ^ rsw) * 8;               // ushort offset within row
    const int rowa = wr + (lane & 15);
    const int rowb = wc + (lane & 15);

    // x source rows for this thread (f32)
    const float* xr0 = xf + (size_t)(m0 + rs) * D_;
    const float* xr1 = xf + (size_t)(m0 + rs + 64) * D_;

    // in-flight f32 x data (16 VGPRs, live across COMPUTE)
    float4 vx0a, vx0b, vx1a, vx1b;

#define STAGE_XLOAD(ktv)                                                     \
    do {                                                                     \
        const int kx = (ktv) * 32 + scol;                                    \
        vx0a = *(const float4*)(xr0 + kx);                                   \
        vx0b = *(const float4*)(xr0 + kx + 4);                               \
        vx1a = *(const float4*)(xr1 + kx);                                   \
        vx1b = *(const float4*)(xr1 + kx + 4);                               \
    } while (0)

#define STAGE_XWRITE(A_)                                                     \
    do {                                                                     \
        uint4 o0, o1;                                                        \
        o0.x = pack2bf(vx0a.x, vx0a.y); o0.y = pack2bf(vx0a.z, vx0a.w);      \
        o0.z = pack2bf(vx0b.x, vx0b.y); o0.w = pack2bf(vx0b.z, vx0b.w);      \
        o1.x = pack2bf(vx1a.x, vx1a.y); o1.y = pack2bf(vx1a.z, vx1a.w);      \
        o1.z = pack2bf(vx1b.x, vx1b.y); o1.w = pack2bf(vx1b.z, vx1b.w);      \
        *(uint4*)&A_[t * 8] = o0;                                            \
        *(uint4*)&A_[(t + 256) * 8] = o1;                                    \
    } while (0)

#define STAGE_W(P_, Q_, ktv)                                                 \
    do {                                                                     \
        const int k0s = (ktv) * 32;                                          \
        _Pragma("unroll")                                                    \
        for (int p = 0; p < 2; ++p) {                                        \
            const int rp = rs + p * 64;                                      \
            const int Lofs = (t + p * 256) * 8;                              \
            async16(W0 + (size_t)rp * D_ + k0s + scol, &P_[Lofs]);           \
            async16(W1 + (size_t)rp * D_ + k0s + scol, &Q_[Lofs]);           \
        }                                                                    \
    } while (0)

// T5: setprio(1) around the pure-MFMA cluster only.
#define COMPUTE(A_, P_, Q_)                                                  \
    do {                                                                     \
        bf16x8 af[4], b08[4], b18[4];                                        \
        _Pragma("unroll")                                                    \
        for (int i = 0; i < 4; ++i)                                          \
            af[i] = *(const bf16x8*)&A_[(rowa + i * 16) * 32 + cs];          \
        _Pragma("unroll")                                                    \
        for (int j = 0; j < 4; ++j) {                                        \
            b08[j] = *(const bf16x8*)&P_[(rowb + j * 16) * 32 + cs];         \
            b18[j] = *(const bf16x8*)&Q_[(rowb + j * 16) * 32 + cs];         \
        }                                                                    \
        __builtin_amdgcn_s_setprio(1);                                       \
        _Pragma("unroll")                                                    \
        for (int i = 0; i < 4; ++i)                                          \
            _Pragma("unroll")                                                \
            for (int j = 0; j < 4; ++j) {                                    \
                acc0[i][j] = __builtin_amdgcn_mfma_f32_16x16x32_bf16(        \
                    af[i], b08[j], acc0[i][j], 0, 0, 0);                     \
                acc1[i][j] = __builtin_amdgcn_mfma_f32_16x16x32_bf16(        \
                    af[i], b18[j], acc1[i][j], 0, 0, 0);                     \
            }                                                                \
        __builtin_amdgcn_s_setprio(0);                                       \
    } while (0)

    // prologue: tile 0 into set 0 (x via regs, W via global_load_lds)
    STAGE_XLOAD(0);
    STAGE_W(B00, B10, 0);
    STAGE_XWRITE(As0);
    __syncthreads();

    for (int kt = 0; kt < 32; kt += 2) {
        // half A: stage kt+1 into set 1, compute kt from set 0.
        // x-loads + W-gload_lds issued BEFORE compute; the pack/ds_write
        // after compute needs only vmcnt(4) (x loads are oldest), W loads
        // stay in flight until the barrier.
        STAGE_XLOAD(kt + 1);
        STAGE_W(B01, B11, kt + 1);
        COMPUTE(As0, B00, B10);
        STAGE_XWRITE(As1);
        __syncthreads();   // set-1 fully staged; set-0 free to overwrite

        // half B: stage kt+2 into set 0, compute kt+1 from set 1
        if (kt + 2 < 32) {
            STAGE_XLOAD(kt + 2);
            STAGE_W(B00, B10, kt + 2);
        }
        COMPUTE(As1, B01, B11);
        if (kt + 2 < 32) STAGE_XWRITE(As0);
        __syncthreads();   // set-0 fully staged; set-1 free to overwrite
    }
#undef STAGE_XLOAD
#undef STAGE_XWRITE
#undef STAGE_W
#undef COMPUTE

    // epilogue: C/D layout col=lane&15, row=quad*4+r
    const int colq = lane & 15;
    const int rowq = quad * 4;

    if (qmode) {
        const float* bias0 = bq + n0;
        const float* bias1 = bq + n0 + 128;
#pragma unroll
        for (int i = 0; i < 4; ++i) {
#pragma unroll
            for (int j = 0; j < 4; ++j) {
                const int c = wc + j * 16 + colq;
                const float bv0 = bias0[c], bv1 = bias1[c];
#pragma unroll
                for (int r = 0; r < 4; ++r) {
                    const int rg = m0 + wr + i * 16 + rowq + r;
                    qb[(size_t)rg * D_ + n0 + c]       = f2bf(acc0[i][j][r] + bv0);
                    qb[(size_t)rg * D_ + n0 + 128 + c] = f2bf(acc1[i][j][r] + bv1);
                }
            }
        }
    } else {
        // kv-mode, row-outer store order (full 128B row segments -> no partial
        // line writeback). weight(localrow) = dec^(31-16(i&1)-4*quad-r).
        const float* bias0 = bk + n0;
        const float* bias1 = bv + n0;
        const int bidx = m0 >> 11;
        const int cbase = ((m0 & 2047) >> 5) + (wr >> 5);
        int cj[4];
        float bv0a[4], bv1a[4], d1a[4], d2a[4], d3a[4], P0a[4], P1a[4];
#pragma unroll
        for (int j = 0; j < 4; ++j) {
            const int c = wc + j * 16 + colq;
            cj[j] = c;
            bv0a[j] = bias0[c];
            bv1a[j] = bias1[c];
            const float dec = decay[n0 + c];
            const float d2 = dec * dec, d4 = d2 * d2;
            const float d8 = d4 * d4, d16 = d8 * d8;
            d1a[j] = dec; d2a[j] = d2; d3a[j] = d2 * dec;
            const float P1 = (quad == 0) ? (d8 * d4) : ((quad == 1) ? d8 : ((quad == 2) ? d4 : 1.0f));
            P1a[j] = P1;
            P0a[j] = d16 * P1;
        }
        float s0[4], s1[4];
#pragma unroll
        for (int j = 0; j < 4; ++j) { s0[j] = 0.f; s1[j] = 0.f; }

#pragma unroll
        for (int i = 0; i < 4; ++i) {
#pragma unroll
            for (int r = 0; r < 4; ++r) {
                const int rg = m0 + wr + i * 16 + rowq + r;
                ushort_t* rowp = kvb + (size_t)rg * D_ + n0;
#pragma unroll
                for (int j = 0; j < 4; ++j) {
                    const float kf = acc0[i][j][r] + bv0a[j];
                    const float vf = acc1[i][j][r] + bv1a[j];
                    const float kvf = kf * vf;
                    rowp[cj[j]] = f2bf(kvf);
                    const float w3 = (r == 0) ? d3a[j] : ((r == 1) ? d2a[j] : ((r == 2) ? d1a[j] : 1.0f));
                    const float wgt = ((i & 1) ? P1a[j] : P0a[j]) * w3;
                    if (i < 2) s0[j] = fmaf(kvf, wgt, s0[j]);
                    else       s1[j] = fmaf(kvf, wgt, s1[j]);
                }
            }
        }
#pragma unroll
        for (int j = 0; j < 4; ++j) {
            s0[j] += __shfl_xor(s0[j], 16, 64);
            s0[j] += __shfl_xor(s0[j], 32, 64);
            s1[j] += __shfl_xor(s1[j], 16, 64);
            s1[j] += __shfl_xor(s1[j], 32, 64);
        }
        if (quad == 0) {
#pragma unroll
            for (int j = 0; j < 4; ++j) {
                const int cg = n0 + cj[j];
                S[(((size_t)bidx * NCHUNK) + cbase) * D_ + cg]     = s0[j];
                S[(((size_t)bidx * NCHUNK) + cbase + 1) * D_ + cg] = s1[j];
            }
        }
    }
}

// ------- scan final: redundant carry-Horner over S, replay, out = q*mem -------
// 1024 blocks (b, chunk, D-half); 128 threads x 4 elems: ushort4 loads
// (8 B/lane) + float4 stores (16 B/lane).  Prefix loop batches 4 rows of
// independent loads per step; fma order exact (bitwise-stable numerics).
__global__ __launch_bounds__(128) void scan_final2(
    const ushort_t* __restrict__ kvb, const ushort_t* __restrict__ qb,
    const float* __restrict__ decay, const float* __restrict__ S,
    float* __restrict__ out) {
    const int bid = blockIdx.x;
    const int b = bid >> 7;             // 128 blocks per batch
    const int c = (bid >> 1) & 63;
    const int dh = bid & 1;
    const int d0 = dh * 512 + threadIdx.x * 4;
    const float4 dc = *(const float4*)&decay[d0];
    float e0 = dc.x, e1 = dc.y, e2 = dc.z, e3 = dc.w;
#pragma unroll
    for (int s = 0; s < 5; ++s) { e0 *= e0; e1 *= e1; e2 *= e2; e3 *= e3; }
    float m0 = 0.f, m1 = 0.f, m2 = 0.f, m3 = 0.f;
    const float* Sb = &S[((size_t)b * NCHUNK) * D_ + d0];
    int cc = 0;
    for (; cc + 4 <= c; cc += 4) {
        const float4 sa = *(const float4*)&Sb[(size_t)(cc + 0) * D_];
        const float4 sb2 = *(const float4*)&Sb[(size_t)(cc + 1) * D_];
        const float4 sc = *(const float4*)&Sb[(size_t)(cc + 2) * D_];
        const float4 sd = *(const float4*)&Sb[(size_t)(cc + 3) * D_];
        m0 = fmaf(e0, m0, sa.x);  m1 = fmaf(e1, m1, sa.y);
        m2 = fmaf(e2, m2, sa.z);  m3 = fmaf(e3, m3, sa.w);
        m0 = fmaf(e0, m0, sb2.x); m1 = fmaf(e1, m1, sb2.y);
        m2 = fmaf(e2, m2, sb2.z); m3 = fmaf(e3, m3, sb2.w);
        m0 = fmaf(e0, m0, sc.x);  m1 = fmaf(e1, m1, sc.y);
        m2 = fmaf(e2, m2, sc.z);  m3 = fmaf(e3, m3, sc.w);
        m0 = fmaf(e0, m0, sd.x);  m1 = fmaf(e1, m1, sd.y);
        m2 = fmaf(e2, m2, sd.z);  m3 = fmaf(e3, m3, sd.w);
    }
    for (; cc < c; ++cc) {
        const float4 s4 = *(const float4*)&Sb[(size_t)cc * D_];
        m0 = fmaf(e0, m0, s4.x);
        m1 = fmaf(e1, m1, s4.y);
        m2 = fmaf(e2, m2, s4.z);
        m3 = fmaf(e3, m3, s4.w);
    }
    size_t base = ((size_t)b * T_ + c * CHUNKLEN) * D_ + d0;
#pragma unroll 8
    for (int i = 0; i < CHUNKLEN; ++i) {
        const size_t o = base + (size_t)i * D_;
        const ushort4 kv = *(const ushort4*)&kvb[o];
        const ushort4 q4 = *(const ushort4*)&qb[o];
        m0 = fmaf(dc.x, m0, bf2f(kv.x));
        m1 = fmaf(dc.y, m1, bf2f(kv.y));
        m2 = fmaf(dc.z, m2, bf2f(kv.z));
        m3 = fmaf(dc.w, m3, bf2f(kv.w));
        *(float4*)&out[o] = make_float4(bf2f(q4.x) * m0, bf2f(q4.y) * m1,
                                        bf2f(q4.z) * m2, bf2f(q4.w) * m3);
    }
}

extern "C" void kernel_launch(void* const* d_in, const int* in_sizes, int n_in,
                              void* d_out, int out_size, void* d_ws, size_t ws_size,
                              hipStream_t stream) {
    const float* x     = (const float*)d_in[0];
    const float* Wq    = (const float*)d_in[1];
    const float* bq    = (const float*)d_in[2];
    const float* Wk    = (const float*)d_in[3];
    const float* bk    = (const float*)d_in[4];
    const float* Wv    = (const float*)d_in[5];
    const float* bv    = (const float*)d_in[6];
    const float* decay = (const float*)d_in[7];
    float* out = (float*)d_out;

    char* ws = (char*)d_ws;
    ushort_t* Wb  = (ushort_t*)(ws);                        //  6,291,456 B
    ushort_t* qb  = (ushort_t*)(ws + 6291456);              // 33,554,432 B
    ushort_t* kvb = (ushort_t*)(ws + 39845888);             // 33,554,432 B
    float*    S   = (float*)(ws + 73400320);                //  2,097,152 B

    ushort_t* Wqb = Wb;
    ushort_t* Wkb = Wb + D_ * D_;
    ushort_t* Wvb = Wb + 2 * D_ * D_;

    const int ncast = 3 * D_ * D_ / 8;
    cast_w<<<ncast / 256, 256, 0, stream>>>(Wq, Wk, Wv, Wb);

    gemm_qkv<<<1536, 256, 0, stream>>>(x, Wqb, Wkb, Wvb, bq, bk, bv, decay,
                                       qb, kvb, S);

    scan_final2<<<B_ * NCHUNK * 2, 128, 0, stream>>>(kvb, qb, decay, S, out);
}